// Round 7
// baseline (139.046 us; speedup 1.0000x reference)
//
#include <hip/hip_runtime.h>
#include <hip/hip_fp16.h>

#define BB 16
#define NN 4096
#define CC 6
#define NSEG (BB * NN)          // 65536 points per direction-role

using half8  = __attribute__((ext_vector_type(8))) _Float16;
using f32x16 = __attribute__((ext_vector_type(16))) float;

// ws layout:
//   half8 Af[2][BB][NN]  @ 0      (2 MB)  A-frag entry per ROW point: (-2h0,-2h1,-2h2,1,1,0,0,0)
//   half8 Bf[2][BB][NN]  @ 2 MB   (2 MB)  B-frag entry per COL point: ( h0, h1, h2,hi,lo,0,0,0)
//   float rx[2][BB][NN]  @ 4 MB   (512 KB) row-point |h|^2 in fp32 (from fp16-rounded coords)

__global__ __launch_bounds__(256) void chamfer_prep_kernel(
    const float* __restrict__ xg, const float* __restrict__ yg,
    half8* __restrict__ Af, half8* __restrict__ Bf, float* __restrict__ rx,
    float* __restrict__ out)
{
    const int p = blockIdx.x * 256 + threadIdx.x;   // 0..131071
    if (p == 0) out[0] = 0.0f;
    const int dir = p >> 16;
    const int rem = p & (NSEG - 1);
    const float* __restrict__ R  = dir ? yg : xg;   // row cloud (min taken FOR its points)
    const float* __restrict__ Cl = dir ? xg : yg;   // col cloud (min taken OVER its points)

    {   // row side
        const float c0 = R[(size_t)rem * CC + 0];
        const float c1 = R[(size_t)rem * CC + 1];
        const float c2 = R[(size_t)rem * CC + 2];
        const _Float16 h0 = (_Float16)c0, h1 = (_Float16)c1, h2 = (_Float16)c2;
        const float f0 = (float)h0, f1 = (float)h1, f2 = (float)h2;
        rx[p] = fmaf(f0, f0, fmaf(f1, f1, f2 * f2));
        half8 a = { (_Float16)(-2.0f) * h0, (_Float16)(-2.0f) * h1, (_Float16)(-2.0f) * h2,
                    (_Float16)1.0f, (_Float16)1.0f,
                    (_Float16)0.0f, (_Float16)0.0f, (_Float16)0.0f };
        Af[p] = a;
    }
    {   // col side: ry carried as hi/lo fp16 pair (K-slots 3,4)
        const float c0 = Cl[(size_t)rem * CC + 0];
        const float c1 = Cl[(size_t)rem * CC + 1];
        const float c2 = Cl[(size_t)rem * CC + 2];
        const _Float16 h0 = (_Float16)c0, h1 = (_Float16)c1, h2 = (_Float16)c2;
        const float f0 = (float)h0, f1 = (float)h1, f2 = (float)h2;
        const float r  = fmaf(f0, f0, fmaf(f1, f1, f2 * f2));
        const _Float16 hi = (_Float16)r;
        const _Float16 lo = (_Float16)(r - (float)hi);
        half8 bfr = { h0, h1, h2, hi, lo,
                      (_Float16)0.0f, (_Float16)0.0f, (_Float16)0.0f };
        Bf[p] = bfr;
    }
}

// grid = 1024 blocks x 256 thr (4 waves). wave -> (dir, b, rowgroup of 32); full j-range.
__global__ __launch_bounds__(256) void chamfer_min_kernel(
    const half8* __restrict__ Af, const half8* __restrict__ Bf,
    const float* __restrict__ rx, float* __restrict__ out)
{
    const int bid   = blockIdx.x;
    const int dir   = bid & 1;
    const int b     = (bid >> 1) & 15;
    const int gq    = bid >> 5;                // 0..31
    const int tid   = threadIdx.x;
    const int w     = tid >> 6;
    const int lane  = tid & 63;
    const int l31   = lane & 31;
    const int hf    = lane >> 5;               // K-half: 0 -> k0..7, 1 -> k8..15 (all-zero)
    const int g     = gq * 4 + w;              // rowgroup 0..127

    const size_t base = ((size_t)dir << 16) + ((size_t)b << 12);

    half8 a = {};
    if (hf == 0) a = Af[base + (size_t)g * 32 + l31];

    const half8* __restrict__ Bb = Bf + base;

    const f32x16 zc = {};                      // persistent zero C operand
    float mn[16];
    #pragma unroll
    for (int s = 0; s < 16; ++s) mn[s] = 3.4e38f;

    // software-pipelined j-tile loop: 128 tiles of 32 cols
    half8 b0 = {}, b1 = {};
    if (hf == 0) { b0 = Bb[l31]; b1 = Bb[32 + l31]; }
    for (int jt = 0; jt < 128; jt += 2) {
        const int nx = (jt + 2 < 128) ? (jt + 2) : 126;   // clamped prefetch
        half8 n0 = {}, n1 = {};
        if (hf == 0) { n0 = Bb[(size_t)nx * 32 + l31]; n1 = Bb[(size_t)(nx + 1) * 32 + l31]; }

        const f32x16 d1 = __builtin_amdgcn_mfma_f32_32x32x16_f16(a, b0, zc, 0, 0, 0);
        const f32x16 d2 = __builtin_amdgcn_mfma_f32_32x32x16_f16(a, b1, zc, 0, 0, 0);
        #pragma unroll
        for (int s = 0; s < 16; ++s)
            mn[s] = fminf(mn[s], fminf(d1[s], d2[s]));    // -> v_min3_f32

        b0 = n0; b1 = n1;
    }

    // cross-lane min over the 32 cols of each half (rows differ only via lane>>5)
    #pragma unroll
    for (int s = 0; s < 16; ++s) {
        float v = mn[s];
        v = fminf(v, __shfl_xor(v, 1,  64));
        v = fminf(v, __shfl_xor(v, 2,  64));
        v = fminf(v, __shfl_xor(v, 4,  64));
        v = fminf(v, __shfl_xor(v, 8,  64));
        v = fminf(v, __shfl_xor(v, 16, 64));
        mn[s] = v;                              // uniform within each 32-lane half
    }

    // add rx per row, sum the 16 rows of this half, one atomic per half-wave
    const float* __restrict__ rxb = rx + base + (size_t)g * 32;
    float s16 = 0.0f;
    #pragma unroll
    for (int s = 0; s < 16; ++s) {
        const int row = (s & 3) + 8 * (s >> 2) + 4 * hf;  // m101 C/D row map
        s16 += fmaxf(mn[s] + rxb[row], 0.0f);             // clamp fp noise at 0
    }
    if (l31 == 0)
        atomicAdd(out, s16 * (1.0f / NSEG));
}

extern "C" void kernel_launch(void* const* d_in, const int* in_sizes, int n_in,
                              void* d_out, int out_size, void* d_ws, size_t ws_size,
                              hipStream_t stream) {
    const float* x = (const float*)d_in[0];
    const float* y = (const float*)d_in[1];
    float* out = (float*)d_out;

    half8* Af = (half8*)d_ws;
    half8* Bf = (half8*)((char*)d_ws + (size_t)2 * NSEG * sizeof(half8));
    float* rx = (float*)((char*)d_ws + (size_t)4 * NSEG * sizeof(half8));

    chamfer_prep_kernel<<<2 * NSEG / 256, 256, 0, stream>>>(x, y, Af, Bf, rx, out);
    chamfer_min_kernel<<<1024, 256, 0, stream>>>(Af, Bf, rx, out);
}

// Round 9
// 93.441 us; speedup vs baseline: 1.4881x; 1.4881x over previous
//
#include <hip/hip_runtime.h>
#include <hip/hip_fp16.h>

#define BB 16
#define NN 4096
#define CC 6
#define NSEG (BB * NN)          // 65536 points per direction-role
#define NTILE 128               // 4096 cols / 32
#define NBLK 1024               // min-kernel blocks

using half8  = __attribute__((ext_vector_type(8))) _Float16;
using f32x16 = __attribute__((ext_vector_type(16))) float;

// ws layout:
//   half8 Af[2][BB][NN] @ 0     (2 MB) A entry per ROW point: (-2h0,-2h1,-2h2,1,1,0,0,0)
//   half8 Bf[2][BB][NN] @ 2 MB  (2 MB) B entry per COL point: ( h0, h1, h2,hi,lo,0,0,0)
//   float rx[2][BB][NN] @ 4 MB  (512 KB) row-point |h|^2 fp32 (also absorbs tail over-read)
//   float bpart[NBLK]   @ 4.5MB (4 KB) per-block partials

__global__ __launch_bounds__(256) void chamfer_prep_kernel(
    const float* __restrict__ xg, const float* __restrict__ yg,
    half8* __restrict__ Af, half8* __restrict__ Bf, float* __restrict__ rx)
{
    const int p   = blockIdx.x * 256 + threadIdx.x;   // 0..131071
    const int dir = p >> 16;
    const int rem = p & (NSEG - 1);
    const float* __restrict__ R  = dir ? yg : xg;   // row cloud (min FOR its points)
    const float* __restrict__ Cl = dir ? xg : yg;   // col cloud (min OVER its points)

    {   // row side
        const float c0 = R[(size_t)rem * CC + 0];
        const float c1 = R[(size_t)rem * CC + 1];
        const float c2 = R[(size_t)rem * CC + 2];
        const _Float16 h0 = (_Float16)c0, h1 = (_Float16)c1, h2 = (_Float16)c2;
        const float f0 = (float)h0, f1 = (float)h1, f2 = (float)h2;
        rx[p] = fmaf(f0, f0, fmaf(f1, f1, f2 * f2));
        half8 a = { (_Float16)(-2.0f) * h0, (_Float16)(-2.0f) * h1,
                    (_Float16)(-2.0f) * h2, (_Float16)1.0f, (_Float16)1.0f,
                    (_Float16)0.0f, (_Float16)0.0f, (_Float16)0.0f };
        Af[p] = a;
    }
    {   // col side: ry as hi/lo fp16 pair in K-slots 3,4
        const float c0 = Cl[(size_t)rem * CC + 0];
        const float c1 = Cl[(size_t)rem * CC + 1];
        const float c2 = Cl[(size_t)rem * CC + 2];
        const _Float16 h0 = (_Float16)c0, h1 = (_Float16)c1, h2 = (_Float16)c2;
        const float f0 = (float)h0, f1 = (float)h1, f2 = (float)h2;
        const float r  = fmaf(f0, f0, fmaf(f1, f1, f2 * f2));
        const _Float16 hi = (_Float16)r;
        const _Float16 lo = (_Float16)(r - (float)hi);
        half8 bfr = { h0, h1, h2, hi, lo,
                      (_Float16)0.0f, (_Float16)0.0f, (_Float16)0.0f };
        Bf[p] = bfr;
    }
}

// grid = 1024 blocks x 256 thr (4 waves). wave -> (dir, b, rowgroup of 32); full j-range.
__global__ __launch_bounds__(256, 4) void chamfer_min_kernel(
    const half8* __restrict__ Af, const half8* __restrict__ Bf,
    const float* __restrict__ rx, float* __restrict__ bpart)
{
    const int bid  = blockIdx.x;
    const int dir  = bid & 1;
    const int b    = (bid >> 1) & 15;
    const int gq   = bid >> 5;                 // 0..31
    const int tid  = threadIdx.x;
    const int w    = tid >> 6;
    const int lane = tid & 63;
    const int l31  = lane & 31;
    const int hf   = lane >> 5;                // K-half select for A (upper = zeros)
    const int g    = gq * 4 + w;               // rowgroup 0..127

    const size_t base = ((size_t)dir << 16) + ((size_t)b << 12);

    half8 a = {};
    if (hf == 0) a = Af[base + (size_t)g * 32 + l31];   // one-time guarded load

    // B loads are unguarded: lanes 32..63 feed k=8..15, which A zeroes out.
    const half8* __restrict__ pb = Bf + base + l31;

    const f32x16 zc = {};
    float mn[16];
    #pragma unroll
    for (int s = 0; s < 16; ++s) mn[s] = 3.4e38f;

    half8 b0 = pb[0];
    half8 b1 = pb[32];
    half8 b2 = pb[64];
    half8 b3 = pb[96];
    const half8* pf = pb + 128;

    for (int jt = 0; jt < NTILE; jt += 4) {
        const f32x16 d0 = __builtin_amdgcn_mfma_f32_32x32x16_f16(a, b0, zc, 0, 0, 0);
        const f32x16 d1 = __builtin_amdgcn_mfma_f32_32x32x16_f16(a, b1, zc, 0, 0, 0);
        const half8 n0 = pf[0];                 // prefetch tiles jt+4, jt+5
        const half8 n1 = pf[32];
        #pragma unroll
        for (int s = 0; s < 16; ++s)
            mn[s] = fminf(mn[s], fminf(d0[s], d1[s]));   // -> v_min3_f32

        const f32x16 e0 = __builtin_amdgcn_mfma_f32_32x32x16_f16(a, b2, zc, 0, 0, 0);
        const f32x16 e1 = __builtin_amdgcn_mfma_f32_32x32x16_f16(a, b3, zc, 0, 0, 0);
        const half8 n2 = pf[64];                // prefetch tiles jt+6, jt+7
        const half8 n3 = pf[96];
        #pragma unroll
        for (int s = 0; s < 16; ++s)
            mn[s] = fminf(mn[s], fminf(e0[s], e1[s]));

        b0 = n0; b1 = n1; b2 = n2; b3 = n3;
        pf += 128;
        // final-iter prefetch over-reads <=2KB past Bf into rx region: valid ws
    }

    // cross-lane min over the 32 cols within each half (halves hold different rows)
    #pragma unroll
    for (int s = 0; s < 16; ++s) {
        float v = mn[s];
        v = fminf(v, __shfl_xor(v, 1,  64));
        v = fminf(v, __shfl_xor(v, 2,  64));
        v = fminf(v, __shfl_xor(v, 4,  64));
        v = fminf(v, __shfl_xor(v, 8,  64));
        v = fminf(v, __shfl_xor(v, 16, 64));
        mn[s] = v;
    }

    // add rx per row, sum this half's 16 rows
    const float* __restrict__ rxb = rx + base + (size_t)g * 32;
    float s16 = 0.0f;
    #pragma unroll
    for (int s = 0; s < 16; ++s) {
        const int row = (s & 3) + 8 * (s >> 2) + 4 * hf;  // C/D row map (m101)
        s16 += fmaxf(mn[s] + rxb[row], 0.0f);             // clamp fp noise at 0
    }

    __shared__ float hsum[8];
    if (l31 == 0) hsum[w * 2 + hf] = s16;
    __syncthreads();
    if (tid == 0) {
        float t = 0.0f;
        #pragma unroll
        for (int k = 0; k < 8; ++k) t += hsum[k];
        bpart[bid] = t;            // plain store — no atomics anywhere
    }
}

__global__ __launch_bounds__(256) void chamfer_final_kernel(
    const float* __restrict__ bpart, float* __restrict__ out)
{
    const int tid = threadIdx.x;
    float s = bpart[tid] + bpart[tid + 256] + bpart[tid + 512] + bpart[tid + 768];
    for (int off = 32; off > 0; off >>= 1)
        s += __shfl_down(s, off, 64);
    __shared__ float wsum[4];
    if ((tid & 63) == 0) wsum[tid >> 6] = s;
    __syncthreads();
    if (tid == 0)
        out[0] = (wsum[0] + wsum[1] + wsum[2] + wsum[3]) * (1.0f / NSEG);
}

extern "C" void kernel_launch(void* const* d_in, const int* in_sizes, int n_in,
                              void* d_out, int out_size, void* d_ws, size_t ws_size,
                              hipStream_t stream) {
    const float* x = (const float*)d_in[0];
    const float* y = (const float*)d_in[1];
    float* out = (float*)d_out;

    half8* Af = (half8*)d_ws;
    half8* Bf = (half8*)((char*)d_ws + (size_t)2 * NSEG * sizeof(half8));
    float* rx = (float*)((char*)d_ws + (size_t)4 * NSEG * sizeof(half8));
    float* bpart = (float*)((char*)rx + (size_t)2 * NSEG * sizeof(float));

    chamfer_prep_kernel<<<2 * NSEG / 256, 256, 0, stream>>>(x, y, Af, Bf, rx);
    chamfer_min_kernel<<<NBLK, 256, 0, stream>>>(Af, Bf, rx, bpart);
    chamfer_final_kernel<<<1, 256, 0, stream>>>(bpart, out);
}